// Round 19
// baseline (47.398 us; speedup 1.0000x reference)
//
#include <hip/hip_runtime.h>

#define HH 256
#define WW 512
#define NCIN 16
#define NCOUT 32
#define NB 4

typedef _Float16 half8 __attribute__((ext_vector_type(8)));
typedef float f32x16 __attribute__((ext_vector_type(16)));

typedef const __attribute__((address_space(1))) void gvoid_t;
typedef __attribute__((address_space(3))) void lvoid_t;

// ws layout
#define XT_OFF   0u                  // fp16 xt: 4*256*512*16 half = 16 MiB
#define WFRAG_OFF 16777216u          // half[9*64*8] = 9216 B
#define YTAB_OFF  (16777216u + 16384u)  // float4[256*9]
#define WS_NEED   (YTAB_OFF + 36864u)

// ---- merged precompute (unchanged from r18) ----
__global__ __launch_bounds__(256) void precompute_all(const float* __restrict__ x,
                                                      const float* __restrict__ w,
                                                      const float* __restrict__ grid,
                                                      _Float16* __restrict__ xh,
                                                      _Float16* __restrict__ wfrag,
                                                      float4* __restrict__ ytab) {
    const float2* g2 = reinterpret_cast<const float2*>(grid);
    if (blockIdx.x < 2048) {                       // x (B,Cin,H,W) -> xh (B,H,W,Cin) fp16
        const int lb = (blockIdx.x & 7) * 256 + (blockIdx.x >> 3);
        const int t = lb * 256 + threadIdx.x;
        const int c = t & (WW - 1);
        const int r = (t >> 9) & (HH - 1);
        const int b = t >> 17;
        const float* xp = x + ((size_t)(b * NCIN) * HH + r) * WW + c;
        half8 h0, h1;
#pragma unroll
        for (int ci = 0; ci < 8; ++ci)  h0[ci] = (_Float16)xp[(size_t)ci * (HH * WW)];
#pragma unroll
        for (int ci = 0; ci < 8; ++ci)  h1[ci] = (_Float16)xp[(size_t)(8 + ci) * (HH * WW)];
        half8* op = reinterpret_cast<half8*>(xh) + (size_t)t * 2;
        op[0] = h0;
        op[1] = h1;
        return;
    }
    if (blockIdx.x < 2066) {                       // wfrag[t][lane][j]
        const int e = (blockIdx.x - 2048) * 256 + threadIdx.x;
        if (e < 4608) {
            const int j = e & 7, lane = (e >> 3) & 63, t = e >> 9;
            const int c32 = lane & 31, h = lane >> 5;
            wfrag[e] = (_Float16)w[c32 * 144 + (h * 8 + j) * 9 + t];
        }
        return;
    }
    const int u = (blockIdx.x - 2066) * 256 + threadIdx.x;
    if (u < HH * 9) {                              // ytab (gy column-independent)
        const int r = u / 9, tap = u - r * 9;
        const int kr = tap / 3, kc = tap - kr * 3;
        const float gy = g2[(size_t)(r * 3 + kr) * 1536 + kc].y;
        const float iy = ((gy + 1.0f) * 0.5f) * (float)(HH - 1);
        const float y0f = floorf(iy);
        const float fy = iy - y0f;
        const int y0 = (int)y0f, y1 = y0 + 1;
        float wy0 = 1.0f - fy, wy1 = fy;
        if (y0 < 0 || y0 > HH - 1) wy0 = 0.0f;
        if (y1 < 0 || y1 > HH - 1) wy1 = 0.0f;
        const int cy0 = min(max(y0, 0), HH - 1), cy1 = min(max(y1, 0), HH - 1);
        ytab[u] = make_float4(wy0, wy1, __int_as_float(cy0), __int_as_float(cy1));
    }
}

// ---- fused sample+conv, round-19: WINDOW-STREAMING gathers.
// Key structural fact: dtheta_off has no column dependence -> ix = (c+delta)*511/512
// per (row,tap). A wave's 32 pixels read a CONTIGUOUS ~34-px window per y-row.
// Stage the 40-px window once (coalesced global_load_lds, counted vmcnt, never 0
// mid-loop), serve the 4 corners from wave-private LDS via ds_read_b128 at
// slot = 2*rel+h, rel = (x0 - firstlane(x0) + 2) & 511. Interp/MFMA bit-identical
// to r18 -> absmax must stay exactly 0.015625.
__global__ __launch_bounds__(256, 4) void sphere_mfma_kernel(const _Float16* __restrict__ xh,
                                                             const float* __restrict__ grid,
                                                             const _Float16* __restrict__ wfrag,
                                                             const float4* __restrict__ ytab,
                                                             const float* __restrict__ bias,
                                                             float* __restrict__ out) {
    // [wave][buf][row][80 slots * 8 halfs] = 4*2*2*640*2B = 20480 B
    __shared__ _Float16 Sl[4][2][2][640];
    const int tid = threadIdx.x, lane = tid & 63, wv = tid >> 6;
    const int c32 = lane & 31, h = lane >> 5;     // pixel-in-tile, channel-half
    const int px = wv * 32 + c32;                 // block-local pixel

    const int lb = ((blockIdx.x & 7) << 9) + (blockIdx.x >> 3);  // 4096 blocks, bijective
    const int pixbase = lb << 7;
    const int b    = pixbase >> 17;
    const int rimg = (pixbase >> 9) & (HH - 1);
    const int c0   = pixbase & (WW - 1);

    // wave-uniform y-side data; row bases in half8(16B) units
    float wy0s[9], wy1s[9];
    int Rb0[9], Rb1[9];
#pragma unroll
    for (int t = 0; t < 9; ++t) {
        const float4 y = ytab[rimg * 9 + t];
        wy0s[t] = y.x;
        wy1s[t] = y.y;
        Rb0[t] = (b * HH + __float_as_int(y.z)) << 10;
        Rb1[t] = (b * HH + __float_as_int(y.w)) << 10;
    }

    // x-side inline from grid (bit-identical expression to r18)
    const float2* g2 = reinterpret_cast<const float2*>(grid);
    const float2* grow = g2 + (size_t)(rimg * 3) * 1536 + (size_t)(c0 + px) * 3;
    float fxs[9];
    int x0s[9];
#pragma unroll
    for (int kr = 0; kr < 3; ++kr)
#pragma unroll
        for (int kc = 0; kc < 3; ++kc) {
            const float gx = grow[(size_t)kr * 1536 + kc].x;
            const float ix = ((gx + 1.0f) * 0.5f) * (float)(WW - 1);
            const float x0f = floorf(ix);
            fxs[kr * 3 + kc] = ix - x0f;
            x0s[kr * 3 + kc] = (int)x0f;
        }

    // W fragments, fragment-ordered: 9 fully-coalesced 16B loads
    const half8* wf8 = reinterpret_cast<const half8*>(wfrag);
    half8 wA[9];
#pragma unroll
    for (int t = 0; t < 9; ++t) wA[t] = wf8[t * 64 + lane];

    const char* xbase = reinterpret_cast<const char*>(xh);
    f32x16 acc = {};
    int xfs[9];

#define ISSUE(tt)                                                                  \
    {                                                                              \
        __builtin_amdgcn_sched_barrier(0);                                         \
        const int xf_ = __builtin_amdgcn_readfirstlane(x0s[tt]);                   \
        xfs[tt] = xf_;                                                             \
        const size_t rb0_ = ((size_t)(unsigned)Rb0[tt]) << 4;                      \
        const size_t rb1_ = ((size_t)(unsigned)Rb1[tt]) << 4;                      \
        const int pu1_ = (xf_ - 2 + (lane >> 1)) & 511;                            \
        const size_t o1_ = (size_t)(pu1_ * 32 + (lane & 1) * 16);                  \
        _Float16* db_ = &Sl[wv][(tt) & 1][0][0];                                   \
        __builtin_amdgcn_global_load_lds((gvoid_t*)(xbase + rb0_ + o1_),           \
                                         (lvoid_t*)db_, 16, 0, 0);                 \
        __builtin_amdgcn_global_load_lds((gvoid_t*)(xbase + rb1_ + o1_),           \
                                         (lvoid_t*)(db_ + 640), 16, 0, 0);         \
        if (lane < 16) {                                                           \
            const int pu2_ = (xf_ - 2 + ((64 + lane) >> 1)) & 511;                 \
            const size_t o2_ = (size_t)(pu2_ * 32 + (lane & 1) * 16);              \
            __builtin_amdgcn_global_load_lds((gvoid_t*)(xbase + rb0_ + o2_),       \
                                             (lvoid_t*)(db_ + 512), 16, 0, 0);     \
            __builtin_amdgcn_global_load_lds((gvoid_t*)(xbase + rb1_ + o2_),       \
                                             (lvoid_t*)(db_ + 640 + 512), 16, 0, 0); \
        }                                                                          \
    }

#define CONSUME(tt, VM)                                                            \
    {                                                                              \
        asm volatile("s_waitcnt vmcnt(" VM ")" ::: "memory");                      \
        __builtin_amdgcn_sched_barrier(0);                                         \
        const int rel_ = (x0s[tt] - xfs[tt] + 2) & 511;                            \
        const _Float16* rb_ = &Sl[wv][(tt) & 1][0][0];                             \
        const int s0_ = (2 * rel_ + h) * 8;                                        \
        const half8 A00 = *reinterpret_cast<const half8*>(rb_ + s0_);              \
        const half8 A01 = *reinterpret_cast<const half8*>(rb_ + s0_ + 16);         \
        const half8 A10 = *reinterpret_cast<const half8*>(rb_ + 640 + s0_);        \
        const half8 A11 = *reinterpret_cast<const half8*>(rb_ + 640 + s0_ + 16);   \
        const float fx_ = fxs[tt];                                                 \
        const float wx0_ = 1.0f - fx_;                                             \
        const float w00_ = wx0_ * wy0s[tt], w01_ = fx_ * wy0s[tt];                 \
        const float w10_ = wx0_ * wy1s[tt], w11_ = fx_ * wy1s[tt];                 \
        const _Float16 W00_ = (_Float16)w00_, W01_ = (_Float16)w01_;               \
        const _Float16 W10_ = (_Float16)w10_, W11_ = (_Float16)w11_;               \
        const half8 B00_ = {W00_, W00_, W00_, W00_, W00_, W00_, W00_, W00_};       \
        const half8 B01_ = {W01_, W01_, W01_, W01_, W01_, W01_, W01_, W01_};       \
        const half8 B10_ = {W10_, W10_, W10_, W10_, W10_, W10_, W10_, W10_};       \
        const half8 B11_ = {W11_, W11_, W11_, W11_, W11_, W11_, W11_, W11_};       \
        half8 pk_ = A00 * B00_;                                                    \
        pk_ += A01 * B01_;                                                         \
        pk_ += A10 * B10_;                                                         \
        pk_ += A11 * B11_;                                                         \
        acc = __builtin_amdgcn_mfma_f32_32x32x16_f16(wA[tt], pk_, acc, 0, 0, 0);   \
    }

    // depth-2 tap ring: 8 loads in flight steady-state; vmcnt(4) waits oldest batch
    ISSUE(0)
    ISSUE(1)
    CONSUME(0, "4") ISSUE(2)
    CONSUME(1, "4") ISSUE(3)
    CONSUME(2, "4") ISSUE(4)
    CONSUME(3, "4") ISSUE(5)
    CONSUME(4, "4") ISSUE(6)
    CONSUME(5, "4") ISSUE(7)
    CONSUME(6, "4") ISSUE(8)
    CONSUME(7, "4")
    CONSUME(8, "0")
#undef ISSUE
#undef CONSUME

    // epilogue: C col=lane&31 (pixel), row=(reg&3)+8*(reg>>2)+4*h (cout)
    const int pix = c0 + wv * 32 + c32;
    float* ob = out + (((size_t)(b * NCOUT) * HH + rimg) * WW) + pix;
#pragma unroll
    for (int reg = 0; reg < 16; ++reg) {
        const int co = (reg & 3) + 8 * (reg >> 2) + 4 * h;
        ob[(size_t)co * (HH * WW)] = acc[reg] + bias[co];
    }
}

// Fallback (no workspace): round-1 direct-gather kernel (verified, ~146us).
__global__ __launch_bounds__(256) void sphere_conv_fallback(const float* __restrict__ x,
                                                            const float* __restrict__ weight,
                                                            const float* __restrict__ bias,
                                                            const float* __restrict__ grid,
                                                            float* __restrict__ out) {
    __shared__ float wlds[NCIN * 9 * NCOUT];
    const int tid = threadIdx.x;
    for (int e = tid; e < NCIN * 9 * NCOUT; e += 256) {
        const int co  = e & (NCOUT - 1);
        const int cik = e >> 5;
        wlds[e] = weight[co * (NCIN * 9) + cik];
    }
    __syncthreads();

    const int pindex = blockIdx.x * 256 + tid;
    const int c = pindex & (WW - 1);
    const int r = (pindex >> 9) & (HH - 1);
    const int b = pindex >> 17;

    float acc[NCOUT];
#pragma unroll
    for (int o = 0; o < NCOUT; ++o) acc[o] = 0.0f;

    const float2* g2 = reinterpret_cast<const float2*>(grid);

#pragma unroll 1
    for (int k = 0; k < 9; ++k) {
        const int kr = k / 3, kc = k - kr * 3;
        const float2 g = g2[(r * 3 + kr) * (WW * 3) + (c * 3 + kc)];
        const float ix = ((g.x + 1.0f) * 0.5f) * (float)(WW - 1);
        const float iy = ((g.y + 1.0f) * 0.5f) * (float)(HH - 1);
        const float x0f = floorf(ix), y0f = floorf(iy);
        const float fx = ix - x0f, fy = iy - y0f;
        const int x0 = (int)x0f, y0 = (int)y0f;
        const int x1 = x0 + 1, y1 = y0 + 1;
        float wx0 = 1.0f - fx, wx1 = fx, wy0 = 1.0f - fy, wy1 = fy;
        if (x0 < 0 || x0 > WW - 1) wx0 = 0.0f;
        if (x1 < 0 || x1 > WW - 1) wx1 = 0.0f;
        if (y0 < 0 || y0 > HH - 1) wy0 = 0.0f;
        if (y1 < 0 || y1 > HH - 1) wy1 = 0.0f;
        const int cx0 = min(max(x0, 0), WW - 1), cx1 = min(max(x1, 0), WW - 1);
        const int cy0 = min(max(y0, 0), HH - 1), cy1 = min(max(y1, 0), HH - 1);
        const float w00 = wx0 * wy0, w01 = wx1 * wy0, w10 = wx0 * wy1, w11 = wx1 * wy1;

#pragma unroll 1
        for (int ci = 0; ci < NCIN; ++ci) {
            const float* xb = x + (size_t)((b * NCIN + ci) * HH) * WW;
            const float a00 = xb[cy0 * WW + cx0];
            const float a01 = xb[cy0 * WW + cx1];
            const float a10 = xb[cy1 * WW + cx0];
            const float a11 = xb[cy1 * WW + cx1];
            const float s = w00 * a00 + w01 * a01 + w10 * a10 + w11 * a11;
            const float4* wl = reinterpret_cast<const float4*>(&wlds[(ci * 9 + k) * NCOUT]);
#pragma unroll
            for (int o = 0; o < 8; ++o) {
                const float4 wv = wl[o];
                acc[o * 4 + 0] += wv.x * s;
                acc[o * 4 + 1] += wv.y * s;
                acc[o * 4 + 2] += wv.z * s;
                acc[o * 4 + 3] += wv.w * s;
            }
        }
    }

    const int obase = ((b * NCOUT) * HH + r) * WW + c;
#pragma unroll
    for (int o = 0; o < NCOUT; ++o) {
        out[obase + o * (HH * WW)] = acc[o] + bias[o];
    }
}

extern "C" void kernel_launch(void* const* d_in, const int* in_sizes, int n_in,
                              void* d_out, int out_size, void* d_ws, size_t ws_size,
                              hipStream_t stream) {
    const float* x    = (const float*)d_in[0];
    const float* w    = (const float*)d_in[1];
    const float* bias = (const float*)d_in[2];
    const float* grid = (const float*)d_in[3];
    float* out = (float*)d_out;

    if (ws_size >= WS_NEED) {
        char* ws = (char*)d_ws;
        _Float16* xh    = (_Float16*)(ws + XT_OFF);
        _Float16* wfrag = (_Float16*)(ws + WFRAG_OFF);
        float4*   ytab  = (float4*)(ws + YTAB_OFF);

        precompute_all<<<2075, 256, 0, stream>>>(x, w, grid, xh, wfrag, ytab);
        sphere_mfma_kernel<<<4096, 256, 0, stream>>>(xh, grid, wfrag, ytab, bias, out);
    } else {
        sphere_conv_fallback<<<2048, 256, 0, stream>>>(x, w, bias, grid, out);
    }
}

// Round 20
// 46.472 us; speedup vs baseline: 1.0199x; 1.0199x over previous
//
#include <hip/hip_runtime.h>

#define HH 256
#define WW 512
#define NCIN 16
#define NCOUT 32
#define NB 4

typedef _Float16 half8 __attribute__((ext_vector_type(8)));
typedef float f32x16 __attribute__((ext_vector_type(16)));

// ws layout
#define XT_OFF   0u                  // fp16 xt: 4*256*512*16 half = 16 MiB
#define WFRAG_OFF 16777216u          // half[9*64*8] = 9216 B
#define YTAB_OFF  (16777216u + 16384u)  // float4[256*9]
#define WS_NEED   (YTAB_OFF + 36864u)

// ---- merged precompute: transpose (blocks 0..2047), wfrag (2048..2065),
// ytab (2066..2074). Conv reads grid directly for the x-side (same bytes).
__global__ __launch_bounds__(256) void precompute_all(const float* __restrict__ x,
                                                      const float* __restrict__ w,
                                                      const float* __restrict__ grid,
                                                      _Float16* __restrict__ xh,
                                                      _Float16* __restrict__ wfrag,
                                                      float4* __restrict__ ytab) {
    const float2* g2 = reinterpret_cast<const float2*>(grid);
    if (blockIdx.x < 2048) {                       // x (B,Cin,H,W) -> xh (B,H,W,Cin) fp16
        const int lb = (blockIdx.x & 7) * 256 + (blockIdx.x >> 3);
        const int t = lb * 256 + threadIdx.x;
        const int c = t & (WW - 1);
        const int r = (t >> 9) & (HH - 1);
        const int b = t >> 17;
        const float* xp = x + ((size_t)(b * NCIN) * HH + r) * WW + c;
        half8 h0, h1;
#pragma unroll
        for (int ci = 0; ci < 8; ++ci)  h0[ci] = (_Float16)xp[(size_t)ci * (HH * WW)];
#pragma unroll
        for (int ci = 0; ci < 8; ++ci)  h1[ci] = (_Float16)xp[(size_t)(8 + ci) * (HH * WW)];
        half8* op = reinterpret_cast<half8*>(xh) + (size_t)t * 2;
        op[0] = h0;
        op[1] = h1;
        return;
    }
    if (blockIdx.x < 2066) {                       // wfrag[t][lane][j]
        const int e = (blockIdx.x - 2048) * 256 + threadIdx.x;
        if (e < 4608) {
            const int j = e & 7, lane = (e >> 3) & 63, t = e >> 9;
            const int c32 = lane & 31, h = lane >> 5;
            wfrag[e] = (_Float16)w[c32 * 144 + (h * 8 + j) * 9 + t];
        }
        return;
    }
    const int u = (blockIdx.x - 2066) * 256 + threadIdx.x;
    if (u < HH * 9) {                              // ytab (gy column-independent)
        const int r = u / 9, tap = u - r * 9;
        const int kr = tap / 3, kc = tap - kr * 3;
        const float gy = g2[(size_t)(r * 3 + kr) * 1536 + kc].y;
        const float iy = ((gy + 1.0f) * 0.5f) * (float)(HH - 1);
        const float y0f = floorf(iy);
        const float fy = iy - y0f;
        const int y0 = (int)y0f, y1 = y0 + 1;
        float wy0 = 1.0f - fy, wy1 = fy;
        if (y0 < 0 || y0 > HH - 1) wy0 = 0.0f;
        if (y1 < 0 || y1 > HH - 1) wy1 = 0.0f;
        const int cy0 = min(max(y0, 0), HH - 1), cy1 = min(max(y1, 0), HH - 1);
        ytab[u] = make_float4(wy0, wy1, __int_as_float(cy0), __int_as_float(cy1));
    }
}

// ---- fused sample+conv (r18, best measured 46.6us total): zero-LDS, wfrag
// fragment-ordered weights, depth-2 register gather pipeline, x-side inline
// from grid, 32x32x16 MFMA per tap, wave-independent (no barrier).
__global__ __launch_bounds__(256, 4) void sphere_mfma_kernel(const _Float16* __restrict__ xh,
                                                             const float* __restrict__ grid,
                                                             const _Float16* __restrict__ wfrag,
                                                             const float4* __restrict__ ytab,
                                                             const float* __restrict__ bias,
                                                             float* __restrict__ out) {
    const int tid = threadIdx.x, lane = tid & 63, wv = tid >> 6;
    const int c32 = lane & 31, h = lane >> 5;     // pixel-in-tile, channel-half
    const int px = wv * 32 + c32;                 // block-local pixel

    const int lb = ((blockIdx.x & 7) << 9) + (blockIdx.x >> 3);  // 4096 blocks, bijective
    const int pixbase = lb << 7;
    const int b    = pixbase >> 17;
    const int rimg = (pixbase >> 9) & (HH - 1);
    const int c0   = pixbase & (WW - 1);

    // wave-uniform y-side data; row bases in half8 units
    float wy0s[9], wy1s[9];
    int Rb0[9], Rb1[9];
#pragma unroll
    for (int t = 0; t < 9; ++t) {
        const float4 y = ytab[rimg * 9 + t];
        wy0s[t] = y.x;
        wy1s[t] = y.y;
        Rb0[t] = (b * HH + __float_as_int(y.z)) << 10;
        Rb1[t] = (b * HH + __float_as_int(y.w)) << 10;
    }

    // x-side from grid directly: 3 rows x 3 adjacent float2 per pixel
    const float2* g2 = reinterpret_cast<const float2*>(grid);
    const float2* grow = g2 + (size_t)(rimg * 3) * 1536 + (size_t)(c0 + px) * 3;
    float fxs[9];
    int x0s[9];
#pragma unroll
    for (int kr = 0; kr < 3; ++kr)
#pragma unroll
        for (int kc = 0; kc < 3; ++kc) {
            const float gx = grow[(size_t)kr * 1536 + kc].x;
            const float ix = ((gx + 1.0f) * 0.5f) * (float)(WW - 1);
            const float x0f = floorf(ix);
            fxs[kr * 3 + kc] = ix - x0f;
            x0s[kr * 3 + kc] = (int)x0f;
        }

    // W fragments, fragment-ordered: 9 fully-coalesced 16B loads
    const half8* wf8 = reinterpret_cast<const half8*>(wfrag);
    half8 wA[9];
#pragma unroll
    for (int t = 0; t < 9; ++t) wA[t] = wf8[t * 64 + lane];

    const half8* x8 = reinterpret_cast<const half8*>(xh);
    f32x16 acc = {};

    half8 A00a, A01a, A10a, A11a, A00b, A01b, A10b, A11b;

#define GLOAD(tt, S)                                                     \
    {                                                                    \
        const int p0_ = Rb0[tt] + (x0s[tt] << 1) + h;                    \
        const int p1_ = Rb1[tt] + (x0s[tt] << 1) + h;                    \
        A00##S = x8[p0_];                                                \
        A01##S = x8[p0_ + 2];                                            \
        A10##S = x8[p1_];                                                \
        A11##S = x8[p1_ + 2];                                            \
    }

#define CONSUME(tt, S)                                                   \
    {                                                                    \
        const float fx_ = fxs[tt];                                       \
        const float wx0_ = 1.0f - fx_;                                   \
        const float w00_ = wx0_ * wy0s[tt], w01_ = fx_ * wy0s[tt];       \
        const float w10_ = wx0_ * wy1s[tt], w11_ = fx_ * wy1s[tt];       \
        const _Float16 W00_ = (_Float16)w00_, W01_ = (_Float16)w01_;     \
        const _Float16 W10_ = (_Float16)w10_, W11_ = (_Float16)w11_;     \
        const half8 B00_ = {W00_, W00_, W00_, W00_, W00_, W00_, W00_, W00_}; \
        const half8 B01_ = {W01_, W01_, W01_, W01_, W01_, W01_, W01_, W01_}; \
        const half8 B10_ = {W10_, W10_, W10_, W10_, W10_, W10_, W10_, W10_}; \
        const half8 B11_ = {W11_, W11_, W11_, W11_, W11_, W11_, W11_, W11_}; \
        half8 pk_ = A00##S * B00_;                                       \
        pk_ += A01##S * B01_;                                            \
        pk_ += A10##S * B10_;                                            \
        pk_ += A11##S * B11_;                                            \
        acc = __builtin_amdgcn_mfma_f32_32x32x16_f16(wA[tt], pk_, acc, 0, 0, 0); \
    }

    // depth-2 software pipeline over taps
    GLOAD(0, a)
    GLOAD(1, b)
    CONSUME(0, a) GLOAD(2, a)
    CONSUME(1, b) GLOAD(3, b)
    CONSUME(2, a) GLOAD(4, a)
    CONSUME(3, b) GLOAD(5, b)
    CONSUME(4, a) GLOAD(6, a)
    CONSUME(5, b) GLOAD(7, b)
    CONSUME(6, a) GLOAD(8, a)
    CONSUME(7, b)
    CONSUME(8, a)
#undef GLOAD
#undef CONSUME

    // epilogue: C col=lane&31 (pixel), row=(reg&3)+8*(reg>>2)+4*h (cout)
    const int pix = c0 + wv * 32 + c32;
    float* ob = out + (((size_t)(b * NCOUT) * HH + rimg) * WW) + pix;
#pragma unroll
    for (int reg = 0; reg < 16; ++reg) {
        const int co = (reg & 3) + 8 * (reg >> 2) + 4 * h;
        ob[(size_t)co * (HH * WW)] = acc[reg] + bias[co];
    }
}

// Fallback (no workspace): round-1 direct-gather kernel (verified, ~146us).
__global__ __launch_bounds__(256) void sphere_conv_fallback(const float* __restrict__ x,
                                                            const float* __restrict__ weight,
                                                            const float* __restrict__ bias,
                                                            const float* __restrict__ grid,
                                                            float* __restrict__ out) {
    __shared__ float wlds[NCIN * 9 * NCOUT];
    const int tid = threadIdx.x;
    for (int e = tid; e < NCIN * 9 * NCOUT; e += 256) {
        const int co  = e & (NCOUT - 1);
        const int cik = e >> 5;
        wlds[e] = weight[co * (NCIN * 9) + cik];
    }
    __syncthreads();

    const int pindex = blockIdx.x * 256 + tid;
    const int c = pindex & (WW - 1);
    const int r = (pindex >> 9) & (HH - 1);
    const int b = pindex >> 17;

    float acc[NCOUT];
#pragma unroll
    for (int o = 0; o < NCOUT; ++o) acc[o] = 0.0f;

    const float2* g2 = reinterpret_cast<const float2*>(grid);

#pragma unroll 1
    for (int k = 0; k < 9; ++k) {
        const int kr = k / 3, kc = k - kr * 3;
        const float2 g = g2[(r * 3 + kr) * (WW * 3) + (c * 3 + kc)];
        const float ix = ((g.x + 1.0f) * 0.5f) * (float)(WW - 1);
        const float iy = ((g.y + 1.0f) * 0.5f) * (float)(HH - 1);
        const float x0f = floorf(ix), y0f = floorf(iy);
        const float fx = ix - x0f, fy = iy - y0f;
        const int x0 = (int)x0f, y0 = (int)y0f;
        const int x1 = x0 + 1, y1 = y0 + 1;
        float wx0 = 1.0f - fx, wx1 = fx, wy0 = 1.0f - fy, wy1 = fy;
        if (x0 < 0 || x0 > WW - 1) wx0 = 0.0f;
        if (x1 < 0 || x1 > WW - 1) wx1 = 0.0f;
        if (y0 < 0 || y0 > HH - 1) wy0 = 0.0f;
        if (y1 < 0 || y1 > HH - 1) wy1 = 0.0f;
        const int cx0 = min(max(x0, 0), WW - 1), cx1 = min(max(x1, 0), WW - 1);
        const int cy0 = min(max(y0, 0), HH - 1), cy1 = min(max(y1, 0), HH - 1);
        const float w00 = wx0 * wy0, w01 = wx1 * wy0, w10 = wx0 * wy1, w11 = wx1 * wy1;

#pragma unroll 1
        for (int ci = 0; ci < NCIN; ++ci) {
            const float* xb = x + (size_t)((b * NCIN + ci) * HH) * WW;
            const float a00 = xb[cy0 * WW + cx0];
            const float a01 = xb[cy0 * WW + cx1];
            const float a10 = xb[cy1 * WW + cx0];
            const float a11 = xb[cy1 * WW + cx1];
            const float s = w00 * a00 + w01 * a01 + w10 * a10 + w11 * a11;
            const float4* wl = reinterpret_cast<const float4*>(&wlds[(ci * 9 + k) * NCOUT]);
#pragma unroll
            for (int o = 0; o < 8; ++o) {
                const float4 wv = wl[o];
                acc[o * 4 + 0] += wv.x * s;
                acc[o * 4 + 1] += wv.y * s;
                acc[o * 4 + 2] += wv.z * s;
                acc[o * 4 + 3] += wv.w * s;
            }
        }
    }

    const int obase = ((b * NCOUT) * HH + r) * WW + c;
#pragma unroll
    for (int o = 0; o < NCOUT; ++o) {
        out[obase + o * (HH * WW)] = acc[o] + bias[o];
    }
}

extern "C" void kernel_launch(void* const* d_in, const int* in_sizes, int n_in,
                              void* d_out, int out_size, void* d_ws, size_t ws_size,
                              hipStream_t stream) {
    const float* x    = (const float*)d_in[0];
    const float* w    = (const float*)d_in[1];
    const float* bias = (const float*)d_in[2];
    const float* grid = (const float*)d_in[3];
    float* out = (float*)d_out;

    if (ws_size >= WS_NEED) {
        char* ws = (char*)d_ws;
        _Float16* xh    = (_Float16*)(ws + XT_OFF);
        _Float16* wfrag = (_Float16*)(ws + WFRAG_OFF);
        float4*   ytab  = (float4*)(ws + YTAB_OFF);

        precompute_all<<<2075, 256, 0, stream>>>(x, w, grid, xh, wfrag, ytab);
        sphere_mfma_kernel<<<4096, 256, 0, stream>>>(xh, grid, wfrag, ytab, bias, out);
    } else {
        sphere_conv_fallback<<<2048, 256, 0, stream>>>(x, w, bias, grid, out);
    }
}